// Round 3
// baseline (132.775 us; speedup 1.0000x reference)
//
#include <hip/hip_runtime.h>

static constexpr int NN = 100000;   // nodes
static constexpr int NE = 500000;   // edges
static constexpr int D  = 32;       // channels
static constexpr int NR = 16;       // relations
static constexpr int CH = 512;      // edges per (type,chunk) block pass in k_edge
static constexpr int NY = 65;       // chunks per type (covers 33280; k-loop handles overflow)

// ---------------- K1: h = x @ W  (+ fused global edge-type histogram) ----
__global__ __launch_bounds__(256) void k_xw_hist(const float* __restrict__ x,
                                                 const float* __restrict__ W,
                                                 const int* __restrict__ et,
                                                 float* __restrict__ h,
                                                 int* __restrict__ cnt) {
    __shared__ float sW[D * D];
    __shared__ int sh[NR];
    if (threadIdx.x < NR) sh[threadIdx.x] = 0;
    for (int i = threadIdx.x; i < D * D; i += 256) sW[i] = W[i];
    __syncthreads();

    // histogram slice (grid-stride over edges)
    for (int e = blockIdx.x * 256 + threadIdx.x; e < NE; e += gridDim.x * 256)
        atomicAdd(&sh[et[e]], 1);

    // h = x @ W for this block's node
    const int n = blockIdx.x * 256 + threadIdx.x;
    if (n < NN) {
        float xr[D];
        const float4* xv = reinterpret_cast<const float4*>(x + (size_t)n * D);
        #pragma unroll
        for (int k = 0; k < 8; ++k) {
            float4 v = xv[k];
            xr[4*k+0] = v.x; xr[4*k+1] = v.y; xr[4*k+2] = v.z; xr[4*k+3] = v.w;
        }
        float4* hv = reinterpret_cast<float4*>(h + (size_t)n * D);
        #pragma unroll
        for (int oc = 0; oc < 8; ++oc) {
            float a0 = 0.f, a1 = 0.f, a2 = 0.f, a3 = 0.f;
            #pragma unroll
            for (int i = 0; i < D; ++i) {
                float xi = xr[i];
                a0 += xi * sW[i*D + 4*oc + 0];
                a1 += xi * sW[i*D + 4*oc + 1];
                a2 += xi * sW[i*D + 4*oc + 2];
                a3 += xi * sW[i*D + 4*oc + 3];
            }
            hv[oc] = make_float4(a0, a1, a2, a3);
        }
    }
    __syncthreads();
    if (threadIdx.x < NR) atomicAdd(&cnt[threadIdx.x], sh[threadIdx.x]);
}

// ---------------- K2a: scatter edges into type buckets (block-aggregated) -
__global__ __launch_bounds__(256) void k_scatter(const int* __restrict__ ei,
                                                 const int* __restrict__ et,
                                                 const int* __restrict__ cnt,
                                                 int* __restrict__ cnt2,
                                                 int2* __restrict__ rec) {
    __shared__ int offs[NR];
    __shared__ int lc[NR];
    __shared__ int lb[NR];
    if (threadIdx.x == 0) {
        int s = 0;
        for (int t = 0; t < NR; ++t) { offs[t] = s; s += cnt[t]; }
    }
    if (threadIdx.x < NR) lc[threadIdx.x] = 0;
    __syncthreads();
    const int e = blockIdx.x * 256 + threadIdx.x;
    int t = 0, rank = 0, s = 0, d = 0;
    const bool v = (e < NE);
    if (v) {
        t = et[e]; s = ei[e]; d = ei[NE + e];
        rank = atomicAdd(&lc[t], 1);
    }
    __syncthreads();
    if (threadIdx.x < NR && lc[threadIdx.x] > 0)
        lb[threadIdx.x] = atomicAdd(&cnt2[threadIdx.x], lc[threadIdx.x]);
    __syncthreads();
    if (v) rec[offs[t] + lb[t] + rank] = make_int2(s, d);
}

// ---------------- K2b: per-edge matvec + scatter-add (type-specialized) --
// blockIdx.x = relation type; R column in registers (lane o holds R[:,o]);
// h rows broadcast from a 2 KB LDS buffer. 256 thr, 2 KB LDS -> 8 blk/CU.
__global__ __launch_bounds__(256) void k_edge(const float* __restrict__ h,
                                              const int2* __restrict__ rec,
                                              const int* __restrict__ cnt,
                                              const float* __restrict__ rel,
                                              float* __restrict__ acc) {
    const int t = blockIdx.x;
    __shared__ int sb[2];
    __shared__ float sh[8][2][D];
    if (threadIdx.x == 0) {
        int s = 0;
        for (int u = 0; u < t; ++u) s += cnt[u];
        sb[0] = s; sb[1] = s + cnt[t];
    }
    __syncthreads();
    const int beg = sb[0], end = sb[1];
    const int o = threadIdx.x & 31;        // output channel
    const int g = threadIdx.x >> 5;        // half-wave group 0..7
    float Rc[32];
    #pragma unroll
    for (int i = 0; i < 32; ++i) Rc[i] = rel[t * 1024 + i * 32 + o];

    for (int start = beg + blockIdx.y * CH; start < end; start += NY * CH) {
        const int stop = min(start + CH, end);
        for (int eA = start + g * 2; eA < stop; eA += 16) {
            const int eB = eA + 1;
            const bool vB = (eB < stop);
            const int2 rA = rec[eA];
            const int2 rB = vB ? rec[eB] : rA;
            const float hA = h[(size_t)rA.x * D + o];
            const float hB = h[(size_t)rB.x * D + o];
            sh[g][0][o] = hA;
            sh[g][1][o] = hB;
            __asm__ volatile("s_waitcnt lgkmcnt(0)" ::: "memory");
            float a0 = 0.f, a1 = 0.f, b0 = 0.f, b1 = 0.f;
            #pragma unroll
            for (int i = 0; i < 32; i += 2) {
                const float pA0 = sh[g][0][i], pA1 = sh[g][0][i + 1];
                const float pB0 = sh[g][1][i], pB1 = sh[g][1][i + 1];
                a0 += pA0 * Rc[i];     a1 += pA1 * Rc[i + 1];
                b0 += pB0 * Rc[i];     b1 += pB1 * Rc[i + 1];
            }
            atomicAdd(acc + (size_t)rA.y * D + o, a0 + a1);
            if (vB) atomicAdd(acc + (size_t)rB.y * D + o, b0 + b1);
            __asm__ volatile("" ::: "memory");   // keep write->read ordering per iter
        }
    }
}

// ---------------- K3a: scores + per-block online (max, sum-exp) ----------
__global__ __launch_bounds__(256) void k_score(const float* __restrict__ acc,
                                               const float* __restrict__ att,
                                               float* __restrict__ scores,
                                               float* __restrict__ pmax,
                                               float* __restrict__ psum) {
    __shared__ float sA[D];
    __shared__ float shm[4], shs[4];
    if (threadIdx.x < D) sA[threadIdx.x] = att[threadIdx.x];
    __syncthreads();
    const int n = blockIdx.x * 256 + threadIdx.x;
    float s = -3.4e38f;
    if (n < NN) {
        const float4* av = reinterpret_cast<const float4*>(acc + (size_t)n * D);
        float v0 = 0.f;
        #pragma unroll
        for (int k = 0; k < 8; ++k) {
            float4 v = av[k];
            v0 += v.x * sA[4*k+0] + v.y * sA[4*k+1] + v.z * sA[4*k+2] + v.w * sA[4*k+3];
        }
        scores[n] = v0;
        s = v0;
    }
    float m = s;
    #pragma unroll
    for (int off = 32; off > 0; off >>= 1)
        m = fmaxf(m, __shfl_down(m, off, 64));
    if ((threadIdx.x & 63) == 0) shm[threadIdx.x >> 6] = m;
    __syncthreads();
    const float bm = fmaxf(fmaxf(shm[0], shm[1]), fmaxf(shm[2], shm[3]));
    float e = (n < NN) ? expf(s - bm) : 0.f;
    #pragma unroll
    for (int off = 32; off > 0; off >>= 1)
        e += __shfl_down(e, off, 64);
    if ((threadIdx.x & 63) == 0) shs[threadIdx.x >> 6] = e;
    __syncthreads();
    if (threadIdx.x == 0) {
        pmax[blockIdx.x] = bm;
        psum[blockIdx.x] = shs[0] + shs[1] + shs[2] + shs[3];
    }
}

// ---------------- K3b: fused combine + scale (every block redoes combine) -
__global__ __launch_bounds__(256) void k_final(float* __restrict__ out,
                                               const float* __restrict__ scores,
                                               const float* __restrict__ pmax,
                                               const float* __restrict__ psum,
                                               int nb) {
    __shared__ float shm[4], shs[4];
    const int tid = threadIdx.x;
    float m = -3.4e38f, s = 0.f;
    for (int i = tid; i < nb; i += 256) {
        const float mi = pmax[i], si = psum[i];
        const float M = fmaxf(m, mi);
        s = s * expf(m - M) + si * expf(mi - M);
        m = M;
    }
    #pragma unroll
    for (int off = 32; off > 0; off >>= 1) {
        const float mo = __shfl_down(m, off, 64);
        const float so = __shfl_down(s, off, 64);
        const float M = fmaxf(m, mo);
        s = s * expf(m - M) + so * expf(mo - M);
        m = M;
    }
    if ((tid & 63) == 0) { shm[tid >> 6] = m; shs[tid >> 6] = s; }
    __syncthreads();
    float M = shm[0], S = shs[0];
    #pragma unroll
    for (int w = 1; w < 4; ++w) {
        const float Mn = fmaxf(M, shm[w]);
        S = S * expf(M - Mn) + shs[w] * expf(shm[w] - Mn);
        M = Mn;
    }
    const int idx = blockIdx.x * 256 + tid;        // float4 index, exact grid
    const int n = idx >> 3;
    const float w = expf(scores[n] - M) / S;
    float4* p = reinterpret_cast<float4*>(out);
    float4 v = p[idx];
    v.x = fmaxf(v.x * w, 0.f);
    v.y = fmaxf(v.y * w, 0.f);
    v.z = fmaxf(v.z * w, 0.f);
    v.w = fmaxf(v.w * w, 0.f);
    p[idx] = v;
}

extern "C" void kernel_launch(void* const* d_in, const int* in_sizes, int n_in,
                              void* d_out, int out_size, void* d_ws, size_t ws_size,
                              hipStream_t stream) {
    const float* x   = (const float*)d_in[0];
    const int*   ei  = (const int*)  d_in[1];
    const int*   et  = (const int*)  d_in[2];
    const float* W   = (const float*)d_in[3];
    const float* rel = (const float*)d_in[4];
    const float* att = (const float*)d_in[5];
    float* out = (float*)d_out;

    // ws layout (floats):
    //   h[NN*D] | rec[NE int2 = 2*NE ints] (scores overlays this after k_edge)
    //   | cnt[16] | cnt2[16] | pmax[512] | psum[512]
    float* h      = (float*)d_ws;
    int2*  rec    = (int2*)(h + (size_t)NN * D);
    int*   cnt    = (int*)(rec + NE);
    int*   cnt2   = cnt + NR;
    float* pmax   = (float*)(cnt2 + NR);
    float* psum   = pmax + 512;
    float* scores = (float*)rec;     // overlay: valid after k_edge

    hipMemsetAsync(d_out, 0, (size_t)NN * D * sizeof(float), stream);
    hipMemsetAsync(cnt, 0, 2 * NR * sizeof(int), stream);

    const int nb_n = (NN + 255) / 256;           // 391
    k_xw_hist<<<nb_n, 256, 0, stream>>>(x, W, et, h, cnt);

    const int nb_e = (NE + 255) / 256;           // 1954
    k_scatter<<<nb_e, 256, 0, stream>>>(ei, et, cnt, cnt2, rec);

    k_edge<<<dim3(NR, NY), 256, 0, stream>>>(h, rec, cnt, rel, out);

    k_score<<<nb_n, 256, 0, stream>>>(out, att, scores, pmax, psum);

    k_final<<<(NN * (D / 4)) / 256, 256, 0, stream>>>(out, scores, pmax, psum, nb_n);
}